// Round 3
// baseline (189.875 us; speedup 1.0000x reference)
//
#include <hip/hip_runtime.h>

// Workspace layout (40 MB total):
//   [0,  8M)  Xb  bf16 [4096][1024]   (reused as Yb after QKV GEMM)
//   [8, 14M)  Wkqv_t bf16 [3072][1024]
//   [14,16M)  Wproj_t bf16 [1024][1024]
//   [16,24M)  Qb bf16 [B,H,T,D]
//   [24,32M)  Kb bf16 [B,H,T,D]
//   [32,40M)  Vb bf16 [B,H,T,D]

#define DEVI __device__ __forceinline__

typedef unsigned short ushort_t;
typedef __attribute__((ext_vector_type(8))) unsigned short ushort8;
typedef __attribute__((ext_vector_type(4))) float f32x4;
typedef __attribute__((ext_vector_type(8))) __bf16 bf16x8;

DEVI unsigned short f2bf(float f) {
  union { float f; unsigned int u; } c; c.f = f;
  unsigned int u = c.u;
  unsigned int r = (u + 0x7FFFu + ((u >> 16) & 1u)) >> 16;
  return (unsigned short)r;
}

DEVI f32x4 mfma16(ushort8 a, ushort8 b, f32x4 c) {
  return __builtin_amdgcn_mfma_f32_16x16x32_bf16(
      __builtin_bit_cast(bf16x8, a), __builtin_bit_cast(bf16x8, b), c, 0, 0, 0);
}

typedef const __attribute__((address_space(1))) void* gptr_t;
typedef __attribute__((address_space(3))) void* lptr_t;
#define GLOAD_LDS16(g, l) \
  __builtin_amdgcn_global_load_lds((gptr_t)(g), (lptr_t)(l), 16, 0, 0)

// ---------------- prep kernels ----------------

__global__ void cast_x_kernel(const float* __restrict__ in,
                              ushort_t* __restrict__ out, int n8) {
  int i = blockIdx.x * blockDim.x + threadIdx.x;
  if (i >= n8) return;
  const f32x4* p = (const f32x4*)in;
  f32x4 a = p[2 * i], b = p[2 * i + 1];
  ushort8 o;
  o[0] = f2bf(a[0]); o[1] = f2bf(a[1]); o[2] = f2bf(a[2]); o[3] = f2bf(a[3]);
  o[4] = f2bf(b[0]); o[5] = f2bf(b[1]); o[6] = f2bf(b[2]); o[7] = f2bf(b[3]);
  ((ushort8*)out)[i] = o;
}

// out[c][r] = bf16(in[r][c]); in is [R][Cin], out is [Cin][R]
__global__ void transpose_cast_kernel(const float* __restrict__ in,
                                      ushort_t* __restrict__ out, int R, int Cin) {
  __shared__ float tile[32][33];
  int c0 = blockIdx.x * 32, r0 = blockIdx.y * 32;
  int tx = threadIdx.x & 31, ty = threadIdx.x >> 5;
#pragma unroll
  for (int it = 0; it < 4; ++it)
    tile[ty + it * 8][tx] = in[(size_t)(r0 + ty + it * 8) * Cin + c0 + tx];
  __syncthreads();
#pragma unroll
  for (int it = 0; it < 4; ++it)
    out[(size_t)(c0 + ty + it * 8) * R + r0 + tx] = f2bf(tile[tx][ty + it * 8]);
}

// ---------------- GEMM: C = A[M,K] * Bt[N,K]^T + bias ----------------
// mode 0: write fp32 out[M][N]
// mode 1: QKV epilogue (scatter q/k/v: bf16 Q/K/V in [B,H,T,D]; fp32 k,v to d_out)
// XCD-aware chunked swizzle: blocks on one XCD form a contiguous by-chunk,
// keeping that chunk's A-panels L2-resident while B streams.

__global__ __launch_bounds__(256) void gemm_bt_kernel(
    const ushort_t* __restrict__ A, const ushort_t* __restrict__ Bt,
    const float* __restrict__ bias, float* __restrict__ outF,
    float* __restrict__ outK, float* __restrict__ outV,
    ushort_t* __restrict__ Qb, ushort_t* __restrict__ Kb, ushort_t* __restrict__ Vb,
    int M, int N, int K, int mode) {
  __shared__ __align__(16) ushort_t As[128 * 64];
  __shared__ __align__(16) ushort_t Bs[128 * 64];
  const int tid = threadIdx.x;
  const int w = tid >> 6, lane = tid & 63;
  const int wr = w >> 1, wc = w & 1;
  // bijective XCD chunk swizzle (nwg divisible by 8)
  const int nbx = gridDim.x;
  const int nwg = nbx * gridDim.y;
  const int orig = blockIdx.x + nbx * blockIdx.y;
  const int tile = (orig & 7) * (nwg >> 3) + (orig >> 3);
  const int bx = tile % nbx, by = tile / nbx;
  const int m0 = by * 128, n0 = bx * 128;
  const int l15 = lane & 15, lhi = lane >> 4;
  const int rowA = lane >> 3, colA = (lane & 7) * 8;

  f32x4 acc[4][4] = {};

  const int nk = K >> 6;
  for (int kt = 0; kt < nk; ++kt) {
    const int k0 = kt << 6;
    __syncthreads();
#pragma unroll
    for (int it = 0; it < 4; ++it) {
      const int rbase = (w * 4 + it) * 8;  // 8 rows per wave-call
      GLOAD_LDS16(A + (size_t)(m0 + rbase + rowA) * K + k0 + colA, &As[rbase * 64]);
      GLOAD_LDS16(Bt + (size_t)(n0 + rbase + rowA) * K + k0 + colA, &Bs[rbase * 64]);
    }
    __syncthreads();
#pragma unroll
    for (int kk = 0; kk < 2; ++kk) {
      const int ko = kk * 32 + lhi * 8;
      ushort8 a[4], b[4];
#pragma unroll
      for (int i = 0; i < 4; ++i)
        a[i] = *(const ushort8*)&As[(wr * 64 + i * 16 + l15) * 64 + ko];
#pragma unroll
      for (int j = 0; j < 4; ++j)
        b[j] = *(const ushort8*)&Bs[(wc * 64 + j * 16 + l15) * 64 + ko];
#pragma unroll
      for (int i = 0; i < 4; ++i)
#pragma unroll
        for (int j = 0; j < 4; ++j) acc[i][j] = mfma16(a[i], b[j], acc[i][j]);
    }
  }

#pragma unroll
  for (int i = 0; i < 4; ++i) {
#pragma unroll
    for (int j = 0; j < 4; ++j) {
      const int nn = n0 + wc * 64 + j * 16 + l15;
      const float bv = bias[nn];
#pragma unroll
      for (int r = 0; r < 4; ++r) {
        const int mm = m0 + wr * 64 + i * 16 + lhi * 4 + r;
        const float v = acc[i][j][r] + bv;
        if (mode == 0) {
          outF[(size_t)mm * N + nn] = v;
        } else {
          const int bb = mm >> 11, t = mm & 2047;
          const int c = nn & 1023, h = c >> 6, d = c & 63;
          const size_t idx = ((size_t)(bb * 16 + h) * 2048 + t) * 64 + d;
          const int sec = nn >> 10;
          if (sec == 0) {
            Qb[idx] = f2bf(v);
          } else if (sec == 1) {
            outK[idx] = v; Kb[idx] = f2bf(v);
          } else {
            outV[idx] = v; Vb[idx] = f2bf(v);
          }
        }
      }
    }
  }
}

// ---------------- flash attention ----------------
// Flat grid of 512 blocks, decoded so all 16 blocks of one (b,h) share
// id % 8 -> same XCD -> K/V stay L2-resident (one HBM fetch per head).
// Block handles q-tiles p and 31-p (balanced: 33 KV steps).
// 4 waves x 16 q-rows. Double-buffered K/V LDS, 1 barrier per KV step.

__global__ __launch_bounds__(256) void attn_kernel(
    const ushort_t* __restrict__ Qb, const ushort_t* __restrict__ Kb,
    const ushort_t* __restrict__ Vb, ushort_t* __restrict__ Yb) {
  __shared__ __align__(16) ushort_t Ks[2][64 * 64];   // K-tile [t][d], swizzled
  __shared__ __align__(16) ushort_t Vt[2][64 * 72];   // V^T [d][k], swizzled
  __shared__ __align__(16) ushort_t Pl[4 * 16 * 72];  // per-wave P [16 q][64 k]
  // XCD-pinning decode: bh % 8 == id % 8
  const int id = blockIdx.x;
  const int xcd = id & 7, win = id >> 3;
  const int bh = xcd + 8 * (win >> 4);
  const int p = win & 15;
  const int b = bh >> 4, h = bh & 15;
  const int tid = threadIdx.x, w = tid >> 6, lane = tid & 63;
  const int l15 = lane & 15, lhi = lane >> 4;
  const size_t base = (size_t)bh * 2048 * 64;
  const float NEG_INF = -__builtin_inff();
  ushort_t* myP = &Pl[w * 16 * 72];

  for (int half = 0; half < 2; ++half) {
    const int qt = half ? (31 - p) : p;
    const int nkt = qt + 1;

    // Q fragments (loop-invariant): lane holds Q[q=l15][k contiguous 8]
    ushort8 qf[2];
    {
      const size_t qrow = base + (size_t)(qt * 64 + w * 16 + l15) * 64;
      qf[0] = *(const ushort8*)&Qb[qrow + lhi * 8];
      qf[1] = *(const ushort8*)&Qb[qrow + 32 + lhi * 8];
    }
    float m_s[4] = {NEG_INF, NEG_INF, NEG_INF, NEG_INF};
    float l_s[4] = {0.f, 0.f, 0.f, 0.f};
    f32x4 o[4] = {};

    // prologue: stage tile 0 into buf 0
    {
#pragma unroll
      for (int it = 0; it < 2; ++it) {
        const int chunk = tid + it * 256;
        const int row = chunk >> 3, g = chunk & 7;
        const int sg = g ^ ((row >> 3) & 7);
        GLOAD_LDS16(Kb + base + (size_t)row * 64 + sg * 8, &Ks[0][chunk * 8]);
      }
      ushort8 vv[2];
#pragma unroll
      for (int it = 0; it < 2; ++it) {
        const int idx = tid + it * 256;
        const int trow = idx >> 3, tcol = (idx & 7) * 8;
        vv[it] = *(const ushort8*)&Vb[base + (size_t)trow * 64 + tcol];
      }
#pragma unroll
      for (int it = 0; it < 2; ++it) {
        const int idx = tid + it * 256;
        const int trow = idx >> 3, tcol = (idx & 7) * 8;
        const int swz = ((trow >> 3) ^ (tcol >> 3)) & 7;
#pragma unroll
        for (int jj = 0; jj < 8; ++jj)
          Vt[0][(tcol + jj) * 72 + swz * 8 + (trow & 7)] = vv[it][jj];
      }
    }
    __syncthreads();

    for (int kt = 0; kt < nkt; ++kt) {
      const int cur = kt & 1, nxt = cur ^ 1;
      const bool pf = (kt + 1 < nkt);
      ushort8 vvn[2];
      if (pf) {
        const size_t tb = base + (size_t)(kt + 1) * 64 * 64;
#pragma unroll
        for (int it = 0; it < 2; ++it) {
          const int chunk = tid + it * 256;
          const int row = chunk >> 3, g = chunk & 7;
          const int sg = g ^ ((row >> 3) & 7);
          GLOAD_LDS16(Kb + tb + (size_t)row * 64 + sg * 8, &Ks[nxt][chunk * 8]);
        }
#pragma unroll
        for (int it = 0; it < 2; ++it) {
          const int idx = tid + it * 256;
          const int trow = idx >> 3, tcol = (idx & 7) * 8;
          vvn[it] = *(const ushort8*)&Vb[tb + (size_t)trow * 64 + tcol];
        }
      }

      // S = Q K^T (per wave: 16 q x 64 k)
      f32x4 s[4] = {};
#pragma unroll
      for (int kk = 0; kk < 2; ++kk) {
#pragma unroll
        for (int j = 0; j < 4; ++j) {
          const int r = j * 16 + l15;
          const int g = (kk * 4 + lhi) ^ ((r >> 3) & 7);
          ushort8 kb = *(const ushort8*)&Ks[cur][r * 64 + g * 8];
          s[j] = mfma16(qf[kk], kb, s[j]);
        }
      }
      // scale + causal mask (diagonal tile only)
      const int row_l = w * 16 + lhi * 4;
#pragma unroll
      for (int j = 0; j < 4; ++j)
#pragma unroll
        for (int r = 0; r < 4; ++r) {
          float v = s[j][r] * 0.125f;
          if (kt == qt && (j * 16 + l15) > (row_l + r)) v = NEG_INF;
          s[j][r] = v;
        }

      // wave-parallel online softmax (rows live across 16-lane groups)
      float mt[4], al[4], rs[4];
#pragma unroll
      for (int r = 0; r < 4; ++r)
        mt[r] = fmaxf(fmaxf(s[0][r], s[1][r]), fmaxf(s[2][r], s[3][r]));
#pragma unroll
      for (int off = 1; off < 16; off <<= 1)
#pragma unroll
        for (int r = 0; r < 4; ++r) mt[r] = fmaxf(mt[r], __shfl_xor(mt[r], off));
#pragma unroll
      for (int r = 0; r < 4; ++r) {
        const float mn = fmaxf(m_s[r], mt[r]);
        al[r] = __expf(m_s[r] - mn);
        m_s[r] = mn;
      }
      float pv[4][4];
#pragma unroll
      for (int j = 0; j < 4; ++j)
#pragma unroll
        for (int r = 0; r < 4; ++r) pv[j][r] = __expf(s[j][r] - m_s[r]);
#pragma unroll
      for (int r = 0; r < 4; ++r) rs[r] = pv[0][r] + pv[1][r] + pv[2][r] + pv[3][r];
#pragma unroll
      for (int off = 1; off < 16; off <<= 1)
#pragma unroll
        for (int r = 0; r < 4; ++r) rs[r] += __shfl_xor(rs[r], off);
#pragma unroll
      for (int r = 0; r < 4; ++r) l_s[r] = al[r] * l_s[r] + rs[r];
#pragma unroll
      for (int df = 0; df < 4; ++df)
#pragma unroll
        for (int r = 0; r < 4; ++r) o[df][r] *= al[r];

      // P -> LDS (wave-private region; no block barrier needed before PV)
#pragma unroll
      for (int j = 0; j < 4; ++j)
#pragma unroll
        for (int r = 0; r < 4; ++r)
          myP[(lhi * 4 + r) * 72 + j * 16 + l15] = f2bf(pv[j][r]);

      // O += P V
#pragma unroll
      for (int kk = 0; kk < 2; ++kk) {
        const int ko = kk * 32 + lhi * 8;
        ushort8 pa = *(const ushort8*)&myP[l15 * 72 + ko];
#pragma unroll
        for (int df = 0; df < 4; ++df) {
          const int r = df * 16 + l15;
          const int g = (kk * 4 + lhi) ^ ((r >> 3) & 7);
          ushort8 vb = *(const ushort8*)&Vt[cur][r * 72 + g * 8];
          o[df] = mfma16(pa, vb, o[df]);
        }
      }

      // write-late: V^T for next tile (loads issued at loop top have landed)
      if (pf) {
#pragma unroll
        for (int it = 0; it < 2; ++it) {
          const int idx = tid + it * 256;
          const int trow = idx >> 3, tcol = (idx & 7) * 8;
          const int swz = ((trow >> 3) ^ (tcol >> 3)) & 7;
#pragma unroll
          for (int jj = 0; jj < 8; ++jj)
            Vt[nxt][(tcol + jj) * 72 + swz * 8 + (trow & 7)] = vvn[it][jj];
        }
      }
      __syncthreads();
    }

    // epilogue: write Y rows for this q-tile
    float inv[4];
#pragma unroll
    for (int r = 0; r < 4; ++r) inv[r] = 1.0f / l_s[r];
    const size_t yrow0 = (size_t)(b * 2048 + qt * 64 + w * 16 + lhi * 4);
#pragma unroll
    for (int df = 0; df < 4; ++df)
#pragma unroll
      for (int r = 0; r < 4; ++r)
        Yb[(yrow0 + r) * 1024 + h * 64 + df * 16 + l15] = f2bf(o[df][r] * inv[r]);
  }
}

// ---------------- launch ----------------

extern "C" void kernel_launch(void* const* d_in, const int* in_sizes, int n_in,
                              void* d_out, int out_size, void* d_ws, size_t ws_size,
                              hipStream_t stream) {
  const float* x      = (const float*)d_in[0];
  const float* W_kqv  = (const float*)d_in[1];
  const float* b_kqv  = (const float*)d_in[2];
  const float* W_proj = (const float*)d_in[3];
  const float* b_proj = (const float*)d_in[4];
  float* out  = (float*)d_out;          // [B,T,C] fp32
  float* outK = out + 4194304;          // [B,H,T,D] fp32
  float* outV = out + 8388608;          // [B,H,T,D] fp32

  char* ws = (char*)d_ws;
  ushort_t* Xb  = (ushort_t*)(ws);
  ushort_t* Wkt = (ushort_t*)(ws + ((size_t)8 << 20));
  ushort_t* Wpt = (ushort_t*)(ws + ((size_t)14 << 20));
  ushort_t* Qb  = (ushort_t*)(ws + ((size_t)16 << 20));
  ushort_t* Kb  = (ushort_t*)(ws + ((size_t)24 << 20));
  ushort_t* Vb  = (ushort_t*)(ws + ((size_t)32 << 20));
  ushort_t* Yb  = Xb;  // Xb dead after QKV GEMM

  cast_x_kernel<<<2048, 256, 0, stream>>>(x, Xb, 524288);
  transpose_cast_kernel<<<dim3(96, 32), 256, 0, stream>>>(W_kqv, Wkt, 1024, 3072);
  transpose_cast_kernel<<<dim3(32, 32), 256, 0, stream>>>(W_proj, Wpt, 1024, 1024);
  gemm_bt_kernel<<<dim3(24, 32), 256, 0, stream>>>(
      Xb, Wkt, b_kqv, nullptr, outK, outV, Qb, Kb, Vb, 4096, 3072, 1024, 1);
  attn_kernel<<<512, 256, 0, stream>>>(Qb, Kb, Vb, Yb);
  gemm_bt_kernel<<<dim3(8, 32), 256, 0, stream>>>(
      Yb, Wpt, b_proj, out, nullptr, nullptr, nullptr, nullptr, nullptr,
      4096, 1024, 1024, 0);
}

// Round 5
// 163.582 us; speedup vs baseline: 1.1607x; 1.1607x over previous
//
#include <hip/hip_runtime.h>

// Workspace layout (40 MB total):
//   [0,  8M)  Xb  bf16 [4096][1024]   (reused as Yb after QKV GEMM)
//   [8, 14M)  Wkqv_t bf16 [3072][1024]
//   [14,16M)  Wproj_t bf16 [1024][1024]
//   [16,24M)  Qb bf16 [B,H,T,D]
//   [24,32M)  Kb bf16 [B,H,T,D]
//   [32,40M)  Vb bf16 [B,H,T,D]

#define DEVI __device__ __forceinline__

typedef unsigned short ushort_t;
typedef unsigned long long u64_t;
typedef __attribute__((ext_vector_type(4))) unsigned short us4;
typedef __attribute__((ext_vector_type(8))) unsigned short ushort8;
typedef __attribute__((ext_vector_type(4))) float f32x4;
typedef __attribute__((ext_vector_type(8))) __bf16 bf16x8;

DEVI unsigned short f2bf(float f) {
  union { float f; unsigned int u; } c; c.f = f;
  unsigned int u = c.u;
  unsigned int r = (u + 0x7FFFu + ((u >> 16) & 1u)) >> 16;
  return (unsigned short)r;
}

DEVI unsigned int pk2(float a, float b) {
  return (unsigned int)f2bf(a) | ((unsigned int)f2bf(b) << 16);
}

DEVI f32x4 mfma16(ushort8 a, ushort8 b, f32x4 c) {
  return __builtin_amdgcn_mfma_f32_16x16x32_bf16(
      __builtin_bit_cast(bf16x8, a), __builtin_bit_cast(bf16x8, b), c, 0, 0, 0);
}

typedef const __attribute__((address_space(1))) void* gptr_t;
typedef __attribute__((address_space(3))) void* lptr_t;
#define GLOAD_LDS16(g, l) \
  __builtin_amdgcn_global_load_lds((gptr_t)(g), (lptr_t)(l), 16, 0, 0)

// ---------------- prep kernels ----------------

__global__ void cast_x_kernel(const float* __restrict__ in,
                              ushort_t* __restrict__ out, int n8) {
  int i = blockIdx.x * blockDim.x + threadIdx.x;
  if (i >= n8) return;
  const f32x4* p = (const f32x4*)in;
  f32x4 a = p[2 * i], b = p[2 * i + 1];
  ushort8 o;
  o[0] = f2bf(a[0]); o[1] = f2bf(a[1]); o[2] = f2bf(a[2]); o[3] = f2bf(a[3]);
  o[4] = f2bf(b[0]); o[5] = f2bf(b[1]); o[6] = f2bf(b[2]); o[7] = f2bf(b[3]);
  ((ushort8*)out)[i] = o;
}

// out[c][r] = bf16(in[r][c]); in is [R][Cin], out is [Cin][R]
__global__ void transpose_cast_kernel(const float* __restrict__ in,
                                      ushort_t* __restrict__ out, int R, int Cin) {
  __shared__ float tile[32][33];
  int c0 = blockIdx.x * 32, r0 = blockIdx.y * 32;
  int tx = threadIdx.x & 31, ty = threadIdx.x >> 5;
#pragma unroll
  for (int it = 0; it < 4; ++it)
    tile[ty + it * 8][tx] = in[(size_t)(r0 + ty + it * 8) * Cin + c0 + tx];
  __syncthreads();
#pragma unroll
  for (int it = 0; it < 4; ++it)
    out[(size_t)(c0 + ty + it * 8) * R + r0 + tx] = f2bf(tile[tx][ty + it * 8]);
}

// ---------------- GEMM: C = A[M,K] * Bt[N,K]^T + bias ----------------
// mode 0: write fp32 out[M][N]
// mode 1: QKV epilogue (scatter q/k/v: bf16 Q/K/V in [B,H,T,D]; fp32 k,v to d_out)

__global__ __launch_bounds__(256) void gemm_bt_kernel(
    const ushort_t* __restrict__ A, const ushort_t* __restrict__ Bt,
    const float* __restrict__ bias, float* __restrict__ outF,
    float* __restrict__ outK, float* __restrict__ outV,
    ushort_t* __restrict__ Qb, ushort_t* __restrict__ Kb, ushort_t* __restrict__ Vb,
    int M, int N, int K, int mode) {
  __shared__ __align__(16) ushort_t As[128 * 64];
  __shared__ __align__(16) ushort_t Bs[128 * 64];
  const int tid = threadIdx.x;
  const int w = tid >> 6, lane = tid & 63;
  const int wr = w >> 1, wc = w & 1;
  // bijective XCD chunk swizzle (nwg divisible by 8)
  const int nbx = gridDim.x;
  const int nwg = nbx * gridDim.y;
  const int orig = blockIdx.x + nbx * blockIdx.y;
  const int tile = (orig & 7) * (nwg >> 3) + (orig >> 3);
  const int bx = tile % nbx, by = tile / nbx;
  const int m0 = by * 128, n0 = bx * 128;
  const int l15 = lane & 15, lhi = lane >> 4;
  const int rowA = lane >> 3, colA = (lane & 7) * 8;

  f32x4 acc[4][4] = {};

  const int nk = K >> 6;
  for (int kt = 0; kt < nk; ++kt) {
    const int k0 = kt << 6;
    __syncthreads();
#pragma unroll
    for (int it = 0; it < 4; ++it) {
      const int rbase = (w * 4 + it) * 8;  // 8 rows per wave-call
      GLOAD_LDS16(A + (size_t)(m0 + rbase + rowA) * K + k0 + colA, &As[rbase * 64]);
      GLOAD_LDS16(Bt + (size_t)(n0 + rbase + rowA) * K + k0 + colA, &Bs[rbase * 64]);
    }
    __syncthreads();
#pragma unroll
    for (int kk = 0; kk < 2; ++kk) {
      const int ko = kk * 32 + lhi * 8;
      ushort8 a[4], b[4];
#pragma unroll
      for (int i = 0; i < 4; ++i)
        a[i] = *(const ushort8*)&As[(wr * 64 + i * 16 + l15) * 64 + ko];
#pragma unroll
      for (int j = 0; j < 4; ++j)
        b[j] = *(const ushort8*)&Bs[(wc * 64 + j * 16 + l15) * 64 + ko];
#pragma unroll
      for (int i = 0; i < 4; ++i)
#pragma unroll
        for (int j = 0; j < 4; ++j) acc[i][j] = mfma16(a[i], b[j], acc[i][j]);
    }
  }

#pragma unroll
  for (int i = 0; i < 4; ++i) {
#pragma unroll
    for (int j = 0; j < 4; ++j) {
      const int nn = n0 + wc * 64 + j * 16 + l15;
      const float bv = bias[nn];
#pragma unroll
      for (int r = 0; r < 4; ++r) {
        const int mm = m0 + wr * 64 + i * 16 + lhi * 4 + r;
        const float v = acc[i][j][r] + bv;
        if (mode == 0) {
          outF[(size_t)mm * N + nn] = v;
        } else {
          const int bb = mm >> 11, t = mm & 2047;
          const int c = nn & 1023, h = c >> 6, d = c & 63;
          const size_t idx = ((size_t)(bb * 16 + h) * 2048 + t) * 64 + d;
          const int sec = nn >> 10;
          if (sec == 0) {
            Qb[idx] = f2bf(v);
          } else if (sec == 1) {
            outK[idx] = v; Kb[idx] = f2bf(v);
          } else {
            outV[idx] = v; Vb[idx] = f2bf(v);
          }
        }
      }
    }
  }
}

// ---------------- flash attention (swapped QK^T, in-lane softmax) ----------------
// Flat grid 512, XCD-pinned: all 16 blocks of one (b,h) share id%8 -> same L2.
// Block handles q-tiles p and 31-p sequentially (balanced 33 KV steps).
// S^T = mfma(K,Q): lane owns q-row (q = w*16+l15) -> softmax in-lane + 2 shfls.
// O^T = mfma(V^T, P^T): rescale/epilogue indexed by q = l15, no broadcasts.
// K: global_load_lds with full-row XOR source-swizzle (conflict-free b128 reads).
// V^T: 2 coalesced b64 loads/thread, t-pair packed, 4 ds_write_b32 (swizzled).
// P^T: 4 ds_write_b64 (packed bf16, swizzled), read back as b128 (B-frag).

__global__ __launch_bounds__(256) void attn_kernel(
    const ushort_t* __restrict__ Qb, const ushort_t* __restrict__ Kb,
    const ushort_t* __restrict__ Vb, ushort_t* __restrict__ Yb) {
  __shared__ __align__(16) ushort_t Ks[2][64 * 64];   // K [t][d], chunk-swizzled
  __shared__ __align__(16) ushort_t Vt[2][64 * 72];   // V^T [d][t], swizzled
  __shared__ __align__(16) ushort_t Pl[4 * 16 * 72];  // per-wave P^T' [q][t], swizzled
  const int id = blockIdx.x;
  const int xcd = id & 7, win = id >> 3;
  const int bh = xcd + 8 * (win >> 4);
  const int p = win & 15;
  const int b = bh >> 4, h = bh & 15;
  const int tid = threadIdx.x, w = tid >> 6, lane = tid & 63;
  const int l15 = lane & 15, lhi = lane >> 4;
  const int swzP = 2 * (l15 & 3);
  const size_t base = (size_t)bh * 2048 * 64;
  const float NEG_INF = -__builtin_inff();
  ushort_t* myP = &Pl[w * 16 * 72];

  // V-staging thread geometry (per it: t0 = even row, 4 d's)
  const int vd0 = (tid & 15) * 4;
  const int vt0b = (tid >> 4) * 2;

  for (int half = 0; half < 2; ++half) {
    const int qt = half ? (31 - p) : p;
    const int nkt = qt + 1;

    // Q fragments (B-operand): lane holds Q[q = w*16+l15][d = kk*32+lhi*8 ..]
    ushort8 qf[2];
    {
      const size_t qrow = base + (size_t)(qt * 64 + w * 16 + l15) * 64;
      qf[0] = *(const ushort8*)&Qb[qrow + lhi * 8];
      qf[1] = *(const ushort8*)&Qb[qrow + 32 + lhi * 8];
    }
    float m_s = NEG_INF, l_s = 0.f;
    f32x4 o[4] = {};

    // prologue: stage tile 0 into buf 0
    {
#pragma unroll
      for (int it = 0; it < 2; ++it) {
        const int chunk = tid + it * 256;
        const int row = chunk >> 3, g = chunk & 7;
        const int sg = g ^ (row & 7);
        GLOAD_LDS16(Kb + base + (size_t)row * 64 + sg * 8, &Ks[0][chunk * 8]);
      }
#pragma unroll
      for (int it = 0; it < 2; ++it) {
        const int t0 = vt0b + it * 32;
        const ushort_t* vp = Vb + base + (size_t)t0 * 64 + vd0;
        u64_t a = *(const u64_t*)vp;
        u64_t c = *(const u64_t*)(vp + 64);
        us4 av = __builtin_bit_cast(us4, a);
        us4 cv = __builtin_bit_cast(us4, c);
#pragma unroll
        for (int i = 0; i < 4; ++i) {
          const int d = vd0 + i;
          const int scg = (t0 >> 3) ^ ((d >> 3) & 7);
          unsigned int wv = (unsigned int)av[i] | ((unsigned int)cv[i] << 16);
          *(unsigned int*)&Vt[0][d * 72 + scg * 8 + (t0 & 7)] = wv;
        }
      }
    }
    __syncthreads();

    for (int kt = 0; kt < nkt; ++kt) {
      const int cur = kt & 1, nxt = cur ^ 1;
      const bool pf = (kt + 1 < nkt);
      u64_t va[2], vc[2];
      if (pf) {
        const size_t tb = base + (size_t)(kt + 1) * 64 * 64;
#pragma unroll
        for (int it = 0; it < 2; ++it) {
          const int chunk = tid + it * 256;
          const int row = chunk >> 3, g = chunk & 7;
          const int sg = g ^ (row & 7);
          GLOAD_LDS16(Kb + tb + (size_t)row * 64 + sg * 8, &Ks[nxt][chunk * 8]);
        }
#pragma unroll
        for (int it = 0; it < 2; ++it) {
          const int t0 = vt0b + it * 32;
          const ushort_t* vp = Vb + tb + (size_t)t0 * 64 + vd0;
          va[it] = *(const u64_t*)vp;
          vc[it] = *(const u64_t*)(vp + 64);
        }
      }

      // S^T = mfma(K, Q): s[j] rows t = j*16+lhi*4+r, col q = w*16+l15
      f32x4 s[4] = {};
#pragma unroll
      for (int kk = 0; kk < 2; ++kk) {
#pragma unroll
        for (int j = 0; j < 4; ++j) {
          const int g = (kk * 4 + lhi) ^ (l15 & 7);
          ushort8 kb = *(const ushort8*)&Ks[cur][(j * 16 + l15) * 64 + g * 8];
          s[j] = mfma16(kb, qf[kk], s[j]);
        }
      }
      // scale + causal mask (diagonal tile only)
      const int qloc = w * 16 + l15;
#pragma unroll
      for (int j = 0; j < 4; ++j)
#pragma unroll
        for (int r = 0; r < 4; ++r) {
          float v = s[j][r] * 0.125f;
          if (kt == qt && (j * 16 + lhi * 4 + r) > qloc) v = NEG_INF;
          s[j][r] = v;
        }

      // in-lane softmax for q-row l15 (partials across lhi group)
      float mrow = s[0][0];
#pragma unroll
      for (int j = 0; j < 4; ++j)
#pragma unroll
        for (int r = 0; r < 4; ++r) mrow = fmaxf(mrow, s[j][r]);
      mrow = fmaxf(mrow, __shfl_xor(mrow, 16));
      mrow = fmaxf(mrow, __shfl_xor(mrow, 32));
      const float mnew = fmaxf(m_s, mrow);
      const float al = __expf(m_s - mnew);
      m_s = mnew;
      float rsum = 0.f;
#pragma unroll
      for (int j = 0; j < 4; ++j)
#pragma unroll
        for (int r = 0; r < 4; ++r) {
          const float pe = __expf(s[j][r] - mnew);
          s[j][r] = pe;
          rsum += pe;
        }
      rsum += __shfl_xor(rsum, 16);
      rsum += __shfl_xor(rsum, 32);
      l_s = al * l_s + rsum;
#pragma unroll
      for (int df = 0; df < 4; ++df)
#pragma unroll
        for (int r = 0; r < 4; ++r) o[df][r] *= al;

      // P^T pack -> LDS (wave-private, swizzled b64 writes)
#pragma unroll
      for (int j = 0; j < 4; ++j) {
        const unsigned int w0 = pk2(s[j][0], s[j][1]);
        const unsigned int w1 = pk2(s[j][2], s[j][3]);
        const u64_t dw = (u64_t)w0 | ((u64_t)w1 << 32);
        const int cg = j * 2 + (lhi >> 1);
        *(u64_t*)&myP[l15 * 72 + ((cg ^ swzP) << 3) + ((lhi & 1) << 2)] = dw;
      }

      // O^T += mfma(V^T-frag, P^T-frag)
#pragma unroll
      for (int kk = 0; kk < 2; ++kk) {
        ushort8 pa = *(const ushort8*)&myP[l15 * 72 + (((kk * 4 + lhi) ^ swzP) << 3)];
#pragma unroll
        for (int df = 0; df < 4; ++df) {
          const int r = df * 16 + l15;
          const int g = (kk * 4 + lhi) ^ ((r >> 3) & 7);
          ushort8 vb = *(const ushort8*)&Vt[cur][r * 72 + g * 8];
          o[df] = mfma16(vb, pa, o[df]);
        }
      }

      // write-late: V^T for next tile
      if (pf) {
#pragma unroll
        for (int it = 0; it < 2; ++it) {
          const int t0 = vt0b + it * 32;
          us4 av = __builtin_bit_cast(us4, va[it]);
          us4 cv = __builtin_bit_cast(us4, vc[it]);
#pragma unroll
          for (int i = 0; i < 4; ++i) {
            const int d = vd0 + i;
            const int scg = (t0 >> 3) ^ ((d >> 3) & 7);
            unsigned int wv = (unsigned int)av[i] | ((unsigned int)cv[i] << 16);
            *(unsigned int*)&Vt[nxt][d * 72 + scg * 8 + (t0 & 7)] = wv;
          }
        }
      }
      __syncthreads();
    }

    // epilogue: lane holds O^T[d = df*16+lhi*4+r][q = w*16+l15]
    const float inv = 1.0f / l_s;
    const size_t yrow = (size_t)(b * 2048 + qt * 64 + w * 16 + l15) * 1024 + h * 64;
#pragma unroll
    for (int df = 0; df < 4; ++df) {
      us4 ov;
#pragma unroll
      for (int r = 0; r < 4; ++r) ov[r] = f2bf(o[df][r] * inv);
      *(us4*)&Yb[yrow + df * 16 + lhi * 4] = ov;
    }
  }
}

// ---------------- launch ----------------

extern "C" void kernel_launch(void* const* d_in, const int* in_sizes, int n_in,
                              void* d_out, int out_size, void* d_ws, size_t ws_size,
                              hipStream_t stream) {
  const float* x      = (const float*)d_in[0];
  const float* W_kqv  = (const float*)d_in[1];
  const float* b_kqv  = (const float*)d_in[2];
  const float* W_proj = (const float*)d_in[3];
  const float* b_proj = (const float*)d_in[4];
  float* out  = (float*)d_out;          // [B,T,C] fp32
  float* outK = out + 4194304;          // [B,H,T,D] fp32
  float* outV = out + 8388608;          // [B,H,T,D] fp32

  char* ws = (char*)d_ws;
  ushort_t* Xb  = (ushort_t*)(ws);
  ushort_t* Wkt = (ushort_t*)(ws + ((size_t)8 << 20));
  ushort_t* Wpt = (ushort_t*)(ws + ((size_t)14 << 20));
  ushort_t* Qb  = (ushort_t*)(ws + ((size_t)16 << 20));
  ushort_t* Kb  = (ushort_t*)(ws + ((size_t)24 << 20));
  ushort_t* Vb  = (ushort_t*)(ws + ((size_t)32 << 20));
  ushort_t* Yb  = Xb;  // Xb dead after QKV GEMM

  cast_x_kernel<<<2048, 256, 0, stream>>>(x, Xb, 524288);
  transpose_cast_kernel<<<dim3(96, 32), 256, 0, stream>>>(W_kqv, Wkt, 1024, 3072);
  transpose_cast_kernel<<<dim3(32, 32), 256, 0, stream>>>(W_proj, Wpt, 1024, 1024);
  gemm_bt_kernel<<<dim3(24, 32), 256, 0, stream>>>(
      Xb, Wkt, b_kqv, nullptr, outK, outV, Qb, Kb, Vb, 4096, 3072, 1024, 1);
  attn_kernel<<<512, 256, 0, stream>>>(Qb, Kb, Vb, Yb);
  gemm_bt_kernel<<<dim3(8, 32), 256, 0, stream>>>(
      Yb, Wpt, b_proj, out, nullptr, nullptr, nullptr, nullptr, nullptr,
      4096, 1024, 1024, 0);
}

// Round 6
// 149.617 us; speedup vs baseline: 1.2691x; 1.0933x over previous
//
#include <hip/hip_runtime.h>

// Workspace layout (40 MB total):
//   [0,  8M)  Xb  bf16 [4096][1024]   (reused as Yb after QKV GEMM)
//   [8, 14M)  Wkqv_t bf16 [3072][1024]
//   [14,16M)  Wproj_t bf16 [1024][1024]
//   [16,24M)  Qb bf16 [B,H,T,D]
//   [24,32M)  Kb bf16 [B,H,T,D]
//   [32,40M)  Vb bf16 [B,H,T,D]

#define DEVI __device__ __forceinline__

typedef unsigned short ushort_t;
typedef unsigned long long u64_t;
typedef __attribute__((ext_vector_type(4))) unsigned short us4;
typedef __attribute__((ext_vector_type(8))) unsigned short ushort8;
typedef __attribute__((ext_vector_type(4))) float f32x4;
typedef __attribute__((ext_vector_type(8))) __bf16 bf16x8;

DEVI unsigned short f2bf(float f) {
  union { float f; unsigned int u; } c; c.f = f;
  unsigned int u = c.u;
  unsigned int r = (u + 0x7FFFu + ((u >> 16) & 1u)) >> 16;
  return (unsigned short)r;
}

DEVI unsigned int pk2(float a, float b) {
  return (unsigned int)f2bf(a) | ((unsigned int)f2bf(b) << 16);
}

DEVI f32x4 mfma16(ushort8 a, ushort8 b, f32x4 c) {
  return __builtin_amdgcn_mfma_f32_16x16x32_bf16(
      __builtin_bit_cast(bf16x8, a), __builtin_bit_cast(bf16x8, b), c, 0, 0, 0);
}

typedef const __attribute__((address_space(1))) void* gptr_t;
typedef __attribute__((address_space(3))) void* lptr_t;
#define GLOAD_LDS16(g, l) \
  __builtin_amdgcn_global_load_lds((gptr_t)(g), (lptr_t)(l), 16, 0, 0)

DEVI void bar() {
  asm volatile("" ::: "memory");
  __builtin_amdgcn_s_barrier();
  asm volatile("" ::: "memory");
}
#define VMCNT(n) asm volatile("s_waitcnt vmcnt(" #n ")" ::: "memory")

// ---------------- prep kernels ----------------

__global__ void cast_x_kernel(const float* __restrict__ in,
                              ushort_t* __restrict__ out, int n8) {
  int i = blockIdx.x * blockDim.x + threadIdx.x;
  if (i >= n8) return;
  const f32x4* p = (const f32x4*)in;
  f32x4 a = p[2 * i], b = p[2 * i + 1];
  ushort8 o;
  o[0] = f2bf(a[0]); o[1] = f2bf(a[1]); o[2] = f2bf(a[2]); o[3] = f2bf(a[3]);
  o[4] = f2bf(b[0]); o[5] = f2bf(b[1]); o[6] = f2bf(b[2]); o[7] = f2bf(b[3]);
  ((ushort8*)out)[i] = o;
}

// out[c][r] = bf16(in[r][c]); in is [R][Cin], out is [Cin][R]
__global__ void transpose_cast_kernel(const float* __restrict__ in,
                                      ushort_t* __restrict__ out, int R, int Cin) {
  __shared__ float tile[32][33];
  int c0 = blockIdx.x * 32, r0 = blockIdx.y * 32;
  int tx = threadIdx.x & 31, ty = threadIdx.x >> 5;
#pragma unroll
  for (int it = 0; it < 4; ++it)
    tile[ty + it * 8][tx] = in[(size_t)(r0 + ty + it * 8) * Cin + c0 + tx];
  __syncthreads();
#pragma unroll
  for (int it = 0; it < 4; ++it)
    out[(size_t)(c0 + ty + it * 8) * R + r0 + tx] = f2bf(tile[tx][ty + it * 8]);
}

// ---------------- GEMM: C = A[M,K] * Bt[N,K]^T + bias ----------------
// mode 0: write fp32 out[M][N]
// mode 1: QKV epilogue (scatter q/k/v: bf16 Q/K/V in [B,H,T,D]; fp32 k,v to d_out)
// Structure: 128x128 tile, BK=64, double-buffered LDS, 2-deep prefetch with
// counted s_waitcnt vmcnt(8) (never 0 in main loop), raw s_barrier, full-row
// XOR swizzle (source-swizzled global_load_lds + swizzled ds_read_b128).

__global__ __launch_bounds__(256) void gemm_bt_kernel(
    const ushort_t* __restrict__ A, const ushort_t* __restrict__ Bt,
    const float* __restrict__ bias, float* __restrict__ outF,
    float* __restrict__ outK, float* __restrict__ outV,
    ushort_t* __restrict__ Qb, ushort_t* __restrict__ Kb, ushort_t* __restrict__ Vb,
    int M, int N, int K, int mode) {
  __shared__ __align__(16) ushort_t As[2][128 * 64];
  __shared__ __align__(16) ushort_t Bs[2][128 * 64];
  const int tid = threadIdx.x;
  const int w = tid >> 6, lane = tid & 63;
  const int wr = w >> 1, wc = w & 1;
  // bijective XCD chunk swizzle (nwg divisible by 8)
  const int nbx = gridDim.x;
  const int nwg = nbx * gridDim.y;
  const int orig = blockIdx.x + nbx * blockIdx.y;
  const int tile = (orig & 7) * (nwg >> 3) + (orig >> 3);
  const int bx = tile % nbx, by = tile / nbx;
  const int m0 = by * 128, n0 = bx * 128;
  const int l15 = lane & 15, lhi = lane >> 4;
  const int rowA = lane >> 3;
  // swizzled source column offset: col group g=lane&7 lands in LDS group g,
  // holding global group g ^ (row&7); row&7 == (lane>>3)&7 for all stages.
  const int sgc = (((lane & 7) ^ ((lane >> 3) & 7)) << 3);

  f32x4 acc[4][4] = {};

  auto stage = [&](int bf, int kt) {
    const size_t k0 = (size_t)kt << 6;
#pragma unroll
    for (int it = 0; it < 4; ++it) {
      const int rbase = (w * 4 + it) * 8;  // 8 rows per wave-call
      GLOAD_LDS16(A + (size_t)(m0 + rbase + rowA) * K + k0 + sgc,
                  &As[bf][rbase * 64]);
      GLOAD_LDS16(Bt + (size_t)(n0 + rbase + rowA) * K + k0 + sgc,
                  &Bs[bf][rbase * 64]);
    }
  };

  const int nk = K >> 6;
  stage(0, 0);
  stage(1, 1);
  VMCNT(8);
  bar();

  for (int kt = 0; kt < nk; ++kt) {
    const int cur = kt & 1;
#pragma unroll
    for (int kk = 0; kk < 2; ++kk) {
      const int gof = (((kk * 4 + lhi) ^ (l15 & 7)) << 3);
      ushort8 a[4], b[4];
#pragma unroll
      for (int i = 0; i < 4; ++i)
        a[i] = *(const ushort8*)&As[cur][(wr * 64 + i * 16 + l15) * 64 + gof];
#pragma unroll
      for (int j = 0; j < 4; ++j)
        b[j] = *(const ushort8*)&Bs[cur][(wc * 64 + j * 16 + l15) * 64 + gof];
#pragma unroll
      for (int i = 0; i < 4; ++i)
#pragma unroll
        for (int j = 0; j < 4; ++j) acc[i][j] = mfma16(a[i], b[j], acc[i][j]);
    }
    if (kt + 2 < nk) {
      bar();  // all waves done reading buf cur
      stage(cur, kt + 2);
      VMCNT(8);  // kt+1's loads landed; kt+2's stay in flight
      bar();
    } else if (kt + 2 == nk) {
      bar();
      VMCNT(0);  // tail: drain last tile's loads
      bar();
    }
  }

#pragma unroll
  for (int i = 0; i < 4; ++i) {
#pragma unroll
    for (int j = 0; j < 4; ++j) {
      const int nn = n0 + wc * 64 + j * 16 + l15;
      const float bv = bias[nn];
#pragma unroll
      for (int r = 0; r < 4; ++r) {
        const int mm = m0 + wr * 64 + i * 16 + lhi * 4 + r;
        const float v = acc[i][j][r] + bv;
        if (mode == 0) {
          outF[(size_t)mm * N + nn] = v;
        } else {
          const int bb = mm >> 11, t = mm & 2047;
          const int c = nn & 1023, h = c >> 6, d = c & 63;
          const size_t idx = ((size_t)(bb * 16 + h) * 2048 + t) * 64 + d;
          const int sec = nn >> 10;
          if (sec == 0) {
            Qb[idx] = f2bf(v);
          } else if (sec == 1) {
            outK[idx] = v; Kb[idx] = f2bf(v);
          } else {
            outV[idx] = v; Vb[idx] = f2bf(v);
          }
        }
      }
    }
  }
}

// ---------------- flash attention (swapped QK^T, in-lane softmax) ----------------
// Flat grid 512, XCD-pinned: all 16 blocks of one (b,h) share id%8 -> same L2.
// Block handles q-tiles p and 31-p sequentially (balanced 33 KV steps).
// S^T = mfma(K,Q): lane owns q-row (q = w*16+l15) -> softmax in-lane + 2 shfls.
// O^T = mfma(V^T, P^T): rescale/epilogue indexed by q = l15, no broadcasts.

__global__ __launch_bounds__(256) void attn_kernel(
    const ushort_t* __restrict__ Qb, const ushort_t* __restrict__ Kb,
    const ushort_t* __restrict__ Vb, ushort_t* __restrict__ Yb) {
  __shared__ __align__(16) ushort_t Ks[2][64 * 64];   // K [t][d], chunk-swizzled
  __shared__ __align__(16) ushort_t Vt[2][64 * 72];   // V^T [d][t], swizzled
  __shared__ __align__(16) ushort_t Pl[4 * 16 * 72];  // per-wave P^T' [q][t], swizzled
  const int id = blockIdx.x;
  const int xcd = id & 7, win = id >> 3;
  const int bh = xcd + 8 * (win >> 4);
  const int p = win & 15;
  const int b = bh >> 4, h = bh & 15;
  const int tid = threadIdx.x, w = tid >> 6, lane = tid & 63;
  const int l15 = lane & 15, lhi = lane >> 4;
  const int swzP = 2 * (l15 & 3);
  const size_t base = (size_t)bh * 2048 * 64;
  const float NEG_INF = -__builtin_inff();
  ushort_t* myP = &Pl[w * 16 * 72];

  // V-staging thread geometry (per it: t0 = even row, 4 d's)
  const int vd0 = (tid & 15) * 4;
  const int vt0b = (tid >> 4) * 2;

  for (int half = 0; half < 2; ++half) {
    const int qt = half ? (31 - p) : p;
    const int nkt = qt + 1;

    // Q fragments (B-operand): lane holds Q[q = w*16+l15][d = kk*32+lhi*8 ..]
    ushort8 qf[2];
    {
      const size_t qrow = base + (size_t)(qt * 64 + w * 16 + l15) * 64;
      qf[0] = *(const ushort8*)&Qb[qrow + lhi * 8];
      qf[1] = *(const ushort8*)&Qb[qrow + 32 + lhi * 8];
    }
    float m_s = NEG_INF, l_s = 0.f;
    f32x4 o[4] = {};

    // prologue: stage tile 0 into buf 0
    {
#pragma unroll
      for (int it = 0; it < 2; ++it) {
        const int chunk = tid + it * 256;
        const int row = chunk >> 3, g = chunk & 7;
        const int sg = g ^ (row & 7);
        GLOAD_LDS16(Kb + base + (size_t)row * 64 + sg * 8, &Ks[0][chunk * 8]);
      }
#pragma unroll
      for (int it = 0; it < 2; ++it) {
        const int t0 = vt0b + it * 32;
        const ushort_t* vp = Vb + base + (size_t)t0 * 64 + vd0;
        u64_t a = *(const u64_t*)vp;
        u64_t c = *(const u64_t*)(vp + 64);
        us4 av = __builtin_bit_cast(us4, a);
        us4 cv = __builtin_bit_cast(us4, c);
#pragma unroll
        for (int i = 0; i < 4; ++i) {
          const int d = vd0 + i;
          const int scg = (t0 >> 3) ^ ((d >> 3) & 7);
          unsigned int wv = (unsigned int)av[i] | ((unsigned int)cv[i] << 16);
          *(unsigned int*)&Vt[0][d * 72 + scg * 8 + (t0 & 7)] = wv;
        }
      }
    }
    __syncthreads();

    for (int kt = 0; kt < nkt; ++kt) {
      const int cur = kt & 1, nxt = cur ^ 1;
      const bool pf = (kt + 1 < nkt);
      u64_t va[2], vc[2];
      if (pf) {
        const size_t tb = base + (size_t)(kt + 1) * 64 * 64;
#pragma unroll
        for (int it = 0; it < 2; ++it) {
          const int chunk = tid + it * 256;
          const int row = chunk >> 3, g = chunk & 7;
          const int sg = g ^ (row & 7);
          GLOAD_LDS16(Kb + tb + (size_t)row * 64 + sg * 8, &Ks[nxt][chunk * 8]);
        }
#pragma unroll
        for (int it = 0; it < 2; ++it) {
          const int t0 = vt0b + it * 32;
          const ushort_t* vp = Vb + tb + (size_t)t0 * 64 + vd0;
          va[it] = *(const u64_t*)vp;
          vc[it] = *(const u64_t*)(vp + 64);
        }
      }

      // S^T = mfma(K, Q): s[j] rows t = j*16+lhi*4+r, col q = w*16+l15
      f32x4 s[4] = {};
#pragma unroll
      for (int kk = 0; kk < 2; ++kk) {
#pragma unroll
        for (int j = 0; j < 4; ++j) {
          const int g = (kk * 4 + lhi) ^ (l15 & 7);
          ushort8 kb = *(const ushort8*)&Ks[cur][(j * 16 + l15) * 64 + g * 8];
          s[j] = mfma16(kb, qf[kk], s[j]);
        }
      }
      // scale + causal mask (diagonal tile only)
      const int qloc = w * 16 + l15;
#pragma unroll
      for (int j = 0; j < 4; ++j)
#pragma unroll
        for (int r = 0; r < 4; ++r) {
          float v = s[j][r] * 0.125f;
          if (kt == qt && (j * 16 + lhi * 4 + r) > qloc) v = NEG_INF;
          s[j][r] = v;
        }

      // in-lane softmax for q-row l15 (partials across lhi group)
      float mrow = s[0][0];
#pragma unroll
      for (int j = 0; j < 4; ++j)
#pragma unroll
        for (int r = 0; r < 4; ++r) mrow = fmaxf(mrow, s[j][r]);
      mrow = fmaxf(mrow, __shfl_xor(mrow, 16));
      mrow = fmaxf(mrow, __shfl_xor(mrow, 32));
      const float mnew = fmaxf(m_s, mrow);
      const float al = __expf(m_s - mnew);
      m_s = mnew;
      float rsum = 0.f;
#pragma unroll
      for (int j = 0; j < 4; ++j)
#pragma unroll
        for (int r = 0; r < 4; ++r) {
          const float pe = __expf(s[j][r] - mnew);
          s[j][r] = pe;
          rsum += pe;
        }
      rsum += __shfl_xor(rsum, 16);
      rsum += __shfl_xor(rsum, 32);
      l_s = al * l_s + rsum;
#pragma unroll
      for (int df = 0; df < 4; ++df)
#pragma unroll
        for (int r = 0; r < 4; ++r) o[df][r] *= al;

      // P^T pack -> LDS (wave-private, swizzled b64 writes)
#pragma unroll
      for (int j = 0; j < 4; ++j) {
        const unsigned int w0 = pk2(s[j][0], s[j][1]);
        const unsigned int w1 = pk2(s[j][2], s[j][3]);
        const u64_t dw = (u64_t)w0 | ((u64_t)w1 << 32);
        const int cg = j * 2 + (lhi >> 1);
        *(u64_t*)&myP[l15 * 72 + ((cg ^ swzP) << 3) + ((lhi & 1) << 2)] = dw;
      }

      // O^T += mfma(V^T-frag, P^T-frag)
#pragma unroll
      for (int kk = 0; kk < 2; ++kk) {
        ushort8 pa = *(const ushort8*)&myP[l15 * 72 + (((kk * 4 + lhi) ^ swzP) << 3)];
#pragma unroll
        for (int df = 0; df < 4; ++df) {
          const int r = df * 16 + l15;
          const int g = (kk * 4 + lhi) ^ ((r >> 3) & 7);
          ushort8 vb = *(const ushort8*)&Vt[cur][r * 72 + g * 8];
          o[df] = mfma16(vb, pa, o[df]);
        }
      }

      // write-late: V^T for next tile
      if (pf) {
#pragma unroll
        for (int it = 0; it < 2; ++it) {
          const int t0 = vt0b + it * 32;
          us4 av = __builtin_bit_cast(us4, va[it]);
          us4 cv = __builtin_bit_cast(us4, vc[it]);
#pragma unroll
          for (int i = 0; i < 4; ++i) {
            const int d = vd0 + i;
            const int scg = (t0 >> 3) ^ ((d >> 3) & 7);
            unsigned int wv = (unsigned int)av[i] | ((unsigned int)cv[i] << 16);
            *(unsigned int*)&Vt[nxt][d * 72 + scg * 8 + (t0 & 7)] = wv;
          }
        }
      }
      __syncthreads();
    }

    // epilogue: lane holds O^T[d = df*16+lhi*4+r][q = w*16+l15]
    const float inv = 1.0f / l_s;
    const size_t yrow = (size_t)(b * 2048 + qt * 64 + w * 16 + l15) * 1024 + h * 64;
#pragma unroll
    for (int df = 0; df < 4; ++df) {
      us4 ov;
#pragma unroll
      for (int r = 0; r < 4; ++r) ov[r] = f2bf(o[df][r] * inv);
      *(us4*)&Yb[yrow + df * 16 + lhi * 4] = ov;
    }
  }
}

// ---------------- launch ----------------

extern "C" void kernel_launch(void* const* d_in, const int* in_sizes, int n_in,
                              void* d_out, int out_size, void* d_ws, size_t ws_size,
                              hipStream_t stream) {
  const float* x      = (const float*)d_in[0];
  const float* W_kqv  = (const float*)d_in[1];
  const float* b_kqv  = (const float*)d_in[2];
  const float* W_proj = (const float*)d_in[3];
  const float* b_proj = (const float*)d_in[4];
  float* out  = (float*)d_out;          // [B,T,C] fp32
  float* outK = out + 4194304;          // [B,H,T,D] fp32
  float* outV = out + 8388608;          // [B,H,T,D] fp32

  char* ws = (char*)d_ws;
  ushort_t* Xb  = (ushort_t*)(ws);
  ushort_t* Wkt = (ushort_t*)(ws + ((size_t)8 << 20));
  ushort_t* Wpt = (ushort_t*)(ws + ((size_t)14 << 20));
  ushort_t* Qb  = (ushort_t*)(ws + ((size_t)16 << 20));
  ushort_t* Kb  = (ushort_t*)(ws + ((size_t)24 << 20));
  ushort_t* Vb  = (ushort_t*)(ws + ((size_t)32 << 20));
  ushort_t* Yb  = Xb;  // Xb dead after QKV GEMM

  cast_x_kernel<<<2048, 256, 0, stream>>>(x, Xb, 524288);
  transpose_cast_kernel<<<dim3(96, 32), 256, 0, stream>>>(W_kqv, Wkt, 1024, 3072);
  transpose_cast_kernel<<<dim3(32, 32), 256, 0, stream>>>(W_proj, Wpt, 1024, 1024);
  gemm_bt_kernel<<<dim3(24, 32), 256, 0, stream>>>(
      Xb, Wkt, b_kqv, nullptr, outK, outV, Qb, Kb, Vb, 4096, 3072, 1024, 1);
  attn_kernel<<<512, 256, 0, stream>>>(Qb, Kb, Vb, Yb);
  gemm_bt_kernel<<<dim3(8, 32), 256, 0, stream>>>(
      Yb, Wpt, b_proj, out, nullptr, nullptr, nullptr, nullptr, nullptr,
      4096, 1024, 1024, 0);
}

// Round 7
// 137.656 us; speedup vs baseline: 1.3793x; 1.0869x over previous
//
#include <hip/hip_runtime.h>

// Workspace layout (40 MB total):
//   [0,  8M)  Xb  bf16 [4096][1024]   (reused as Yb after QKV GEMM)
//   [8, 14M)  Wkqv_t bf16 [3072][1024]
//   [14,16M)  Wproj_t bf16 [1024][1024]
//   [16,24M)  Qb bf16 [B,H,T,D]  (pre-scaled by 0.125*log2e)
//   [24,32M)  Kb bf16 [B,H,T,D]
//   [32,40M)  Vb bf16 [B,H,T,D]

#define DEVI __device__ __forceinline__

typedef unsigned short ushort_t;
typedef unsigned long long u64_t;
typedef __attribute__((ext_vector_type(4))) unsigned short us4;
typedef __attribute__((ext_vector_type(8))) unsigned short ushort8;
typedef __attribute__((ext_vector_type(4))) float f32x4;
typedef __attribute__((ext_vector_type(8))) __bf16 bf16x8;

DEVI unsigned short f2bf(float f) {
  union { float f; unsigned int u; } c; c.f = f;
  unsigned int u = c.u;
  unsigned int r = (u + 0x7FFFu + ((u >> 16) & 1u)) >> 16;
  return (unsigned short)r;
}

// exp2 via raw v_exp_f32 (1 VALU trans op; s_nop covers the RAW hazard)
DEVI float exp2v(float x) {
  float r;
  asm("v_exp_f32 %0, %1\n\ts_nop 0" : "=v"(r) : "v"(x));
  return r;
}

// pack 2 fp32 -> 2 bf16 (RNE) in one instruction
DEVI unsigned int cvtpk(float lo, float hi) {
  unsigned int r;
  asm("v_cvt_pk_bf16_f32 %0, %1, %2" : "=v"(r) : "v"(lo), "v"(hi));
  return r;
}

DEVI f32x4 mfma16(ushort8 a, ushort8 b, f32x4 c) {
  return __builtin_amdgcn_mfma_f32_16x16x32_bf16(
      __builtin_bit_cast(bf16x8, a), __builtin_bit_cast(bf16x8, b), c, 0, 0, 0);
}

typedef const __attribute__((address_space(1))) void* gptr_t;
typedef __attribute__((address_space(3))) void* lptr_t;
#define GLOAD_LDS16(g, l) \
  __builtin_amdgcn_global_load_lds((gptr_t)(g), (lptr_t)(l), 16, 0, 0)

DEVI void bar() {
  asm volatile("" ::: "memory");
  __builtin_amdgcn_s_barrier();
  asm volatile("" ::: "memory");
}
#define VMCNT(n) asm volatile("s_waitcnt vmcnt(" #n ")" ::: "memory")

// ---------------- prep kernels ----------------

__global__ void cast_x_kernel(const float* __restrict__ in,
                              ushort_t* __restrict__ out, int n8) {
  int i = blockIdx.x * blockDim.x + threadIdx.x;
  if (i >= n8) return;
  const f32x4* p = (const f32x4*)in;
  f32x4 a = p[2 * i], b = p[2 * i + 1];
  ushort8 o;
  o[0] = f2bf(a[0]); o[1] = f2bf(a[1]); o[2] = f2bf(a[2]); o[3] = f2bf(a[3]);
  o[4] = f2bf(b[0]); o[5] = f2bf(b[1]); o[6] = f2bf(b[2]); o[7] = f2bf(b[3]);
  ((ushort8*)out)[i] = o;
}

// out[c][r] = bf16(in[r][c]); in is [R][Cin], out is [Cin][R]
__global__ void transpose_cast_kernel(const float* __restrict__ in,
                                      ushort_t* __restrict__ out, int R, int Cin) {
  __shared__ float tile[32][33];
  int c0 = blockIdx.x * 32, r0 = blockIdx.y * 32;
  int tx = threadIdx.x & 31, ty = threadIdx.x >> 5;
#pragma unroll
  for (int it = 0; it < 4; ++it)
    tile[ty + it * 8][tx] = in[(size_t)(r0 + ty + it * 8) * Cin + c0 + tx];
  __syncthreads();
#pragma unroll
  for (int it = 0; it < 4; ++it)
    out[(size_t)(c0 + ty + it * 8) * R + r0 + tx] = f2bf(tile[tx][ty + it * 8]);
}

// ---------------- GEMM: C = A[M,K] * Bt[N,K]^T + bias ----------------
// mode 0: write fp32 out[M][N]
// mode 1: QKV epilogue (scatter q/k/v; Qb pre-scaled by 0.125*log2e for attn)
// 128x128 tile, BK=64, dbuf LDS, 2-deep prefetch, counted vmcnt(8), raw
// s_barrier, full-row XOR swizzle (source-swizzled gload_lds + swizzled reads).

__global__ __launch_bounds__(256) void gemm_bt_kernel(
    const ushort_t* __restrict__ A, const ushort_t* __restrict__ Bt,
    const float* __restrict__ bias, float* __restrict__ outF,
    float* __restrict__ outK, float* __restrict__ outV,
    ushort_t* __restrict__ Qb, ushort_t* __restrict__ Kb, ushort_t* __restrict__ Vb,
    int M, int N, int K, int mode) {
  __shared__ __align__(16) ushort_t As[2][128 * 64];
  __shared__ __align__(16) ushort_t Bs[2][128 * 64];
  const int tid = threadIdx.x;
  const int w = tid >> 6, lane = tid & 63;
  const int wr = w >> 1, wc = w & 1;
  // bijective XCD chunk swizzle (nwg divisible by 8)
  const int nbx = gridDim.x;
  const int nwg = nbx * gridDim.y;
  const int orig = blockIdx.x + nbx * blockIdx.y;
  const int tile = (orig & 7) * (nwg >> 3) + (orig >> 3);
  const int bx = tile % nbx, by = tile / nbx;
  const int m0 = by * 128, n0 = bx * 128;
  const int l15 = lane & 15, lhi = lane >> 4;
  const int rowA = lane >> 3;
  const int sgc = (((lane & 7) ^ ((lane >> 3) & 7)) << 3);

  f32x4 acc[4][4] = {};

  auto stage = [&](int bf, int kt) {
    const size_t k0 = (size_t)kt << 6;
#pragma unroll
    for (int it = 0; it < 4; ++it) {
      const int rbase = (w * 4 + it) * 8;  // 8 rows per wave-call
      GLOAD_LDS16(A + (size_t)(m0 + rbase + rowA) * K + k0 + sgc,
                  &As[bf][rbase * 64]);
      GLOAD_LDS16(Bt + (size_t)(n0 + rbase + rowA) * K + k0 + sgc,
                  &Bs[bf][rbase * 64]);
    }
  };

  const int nk = K >> 6;
  stage(0, 0);
  stage(1, 1);
  VMCNT(8);
  bar();

  for (int kt = 0; kt < nk; ++kt) {
    const int cur = kt & 1;
#pragma unroll
    for (int kk = 0; kk < 2; ++kk) {
      const int gof = (((kk * 4 + lhi) ^ (l15 & 7)) << 3);
      ushort8 a[4], b[4];
#pragma unroll
      for (int i = 0; i < 4; ++i)
        a[i] = *(const ushort8*)&As[cur][(wr * 64 + i * 16 + l15) * 64 + gof];
#pragma unroll
      for (int j = 0; j < 4; ++j)
        b[j] = *(const ushort8*)&Bs[cur][(wc * 64 + j * 16 + l15) * 64 + gof];
#pragma unroll
      for (int i = 0; i < 4; ++i)
#pragma unroll
        for (int j = 0; j < 4; ++j) acc[i][j] = mfma16(a[i], b[j], acc[i][j]);
    }
    if (kt + 2 < nk) {
      bar();  // all waves done reading buf cur
      stage(cur, kt + 2);
      VMCNT(8);  // kt+1's loads landed; kt+2's stay in flight
      bar();
    } else if (kt + 2 == nk) {
      bar();
      VMCNT(0);  // tail: drain last tile's loads
      bar();
    }
  }

  const float QSCALE = 0.18033688011112042f;  // 0.125 * log2(e)
#pragma unroll
  for (int i = 0; i < 4; ++i) {
#pragma unroll
    for (int j = 0; j < 4; ++j) {
      const int nn = n0 + wc * 64 + j * 16 + l15;
      const float bv = bias[nn];
#pragma unroll
      for (int r = 0; r < 4; ++r) {
        const int mm = m0 + wr * 64 + i * 16 + lhi * 4 + r;
        const float v = acc[i][j][r] + bv;
        if (mode == 0) {
          outF[(size_t)mm * N + nn] = v;
        } else {
          const int bb = mm >> 11, t = mm & 2047;
          const int c = nn & 1023, h = c >> 6, d = c & 63;
          const size_t idx = ((size_t)(bb * 16 + h) * 2048 + t) * 64 + d;
          const int sec = nn >> 10;
          if (sec == 0) {
            Qb[idx] = f2bf(v * QSCALE);
          } else if (sec == 1) {
            outK[idx] = v; Kb[idx] = f2bf(v);
          } else {
            outV[idx] = v; Vb[idx] = f2bf(v);
          }
        }
      }
    }
  }
}

// ---------------- flash attention (swapped QK^T, in-lane softmax) ----------------
// Grid 1024 (one q-tile each), XCD-pinned (id%8 == bh%8), long-tiles-first.
// S^T = mfma(K,Q) in exp2 domain (Q pre-scaled by 0.125*log2e).
// Defer-max (THR=8): skip O-rescale while running max grows slowly.
// P-pack via v_cvt_pk_bf16_f32. K via swizzled global_load_lds; V^T reg-staged.

__global__ __launch_bounds__(256) void attn_kernel(
    const ushort_t* __restrict__ Qb, const ushort_t* __restrict__ Kb,
    const ushort_t* __restrict__ Vb, ushort_t* __restrict__ Yb) {
  __shared__ __align__(16) ushort_t Ks[2][64 * 64];   // K [t][d], chunk-swizzled
  __shared__ __align__(16) ushort_t Vt[2][64 * 72];   // V^T [d][t], swizzled
  __shared__ __align__(16) ushort_t Pl[4 * 16 * 72];  // per-wave P^T' [q][t], swizzled
  const int id = blockIdx.x;
  const int xcd = id & 7, win = id >> 3;
  const int qt = 31 - (win >> 2);     // longest blocks first
  const int bh = xcd + 8 * (win & 3);
  const int b = bh >> 4, h = bh & 15;
  const int tid = threadIdx.x, w = tid >> 6, lane = tid & 63;
  const int l15 = lane & 15, lhi = lane >> 4;
  const int swzP = 2 * (l15 & 3);
  const size_t base = (size_t)bh * 2048 * 64;
  const float NEG_INF = -__builtin_inff();
  ushort_t* myP = &Pl[w * 16 * 72];

  // V-staging thread geometry (per it: t0 = even row, 4 d's)
  const int vd0 = (tid & 15) * 4;
  const int vt0b = (tid >> 4) * 2;

  const int nkt = qt + 1;

  // Q fragments (B-operand): lane holds Q[q = w*16+l15][d = kk*32+lhi*8 ..]
  ushort8 qf[2];
  {
    const size_t qrow = base + (size_t)(qt * 64 + w * 16 + l15) * 64;
    qf[0] = *(const ushort8*)&Qb[qrow + lhi * 8];
    qf[1] = *(const ushort8*)&Qb[qrow + 32 + lhi * 8];
  }
  float m_s = NEG_INF, l_s = 0.f;
  f32x4 o[4] = {};

  // prologue: stage tile 0 into buf 0
  {
#pragma unroll
    for (int it = 0; it < 2; ++it) {
      const int chunk = tid + it * 256;
      const int row = chunk >> 3, g = chunk & 7;
      const int sg = g ^ (row & 7);
      GLOAD_LDS16(Kb + base + (size_t)row * 64 + sg * 8, &Ks[0][chunk * 8]);
    }
#pragma unroll
    for (int it = 0; it < 2; ++it) {
      const int t0 = vt0b + it * 32;
      const ushort_t* vp = Vb + base + (size_t)t0 * 64 + vd0;
      u64_t a = *(const u64_t*)vp;
      u64_t c = *(const u64_t*)(vp + 64);
      us4 av = __builtin_bit_cast(us4, a);
      us4 cv = __builtin_bit_cast(us4, c);
#pragma unroll
      for (int i = 0; i < 4; ++i) {
        const int d = vd0 + i;
        const int scg = (t0 >> 3) ^ ((d >> 3) & 7);
        unsigned int wv = (unsigned int)av[i] | ((unsigned int)cv[i] << 16);
        *(unsigned int*)&Vt[0][d * 72 + scg * 8 + (t0 & 7)] = wv;
      }
    }
  }
  __syncthreads();

  for (int kt = 0; kt < nkt; ++kt) {
    const int cur = kt & 1, nxt = cur ^ 1;
    const bool pf = (kt + 1 < nkt);
    u64_t va[2], vc[2];
    if (pf) {
      const size_t tb = base + (size_t)(kt + 1) * 64 * 64;
#pragma unroll
      for (int it = 0; it < 2; ++it) {
        const int chunk = tid + it * 256;
        const int row = chunk >> 3, g = chunk & 7;
        const int sg = g ^ (row & 7);
        GLOAD_LDS16(Kb + tb + (size_t)row * 64 + sg * 8, &Ks[nxt][chunk * 8]);
      }
#pragma unroll
      for (int it = 0; it < 2; ++it) {
        const int t0 = vt0b + it * 32;
        const ushort_t* vp = Vb + tb + (size_t)t0 * 64 + vd0;
        va[it] = *(const u64_t*)vp;
        vc[it] = *(const u64_t*)(vp + 64);
      }
    }

    // S^T = mfma(K, Q): s[j] rows t = j*16+lhi*4+r, col q = w*16+l15
    f32x4 s[4] = {};
#pragma unroll
    for (int kk = 0; kk < 2; ++kk) {
#pragma unroll
      for (int j = 0; j < 4; ++j) {
        const int g = (kk * 4 + lhi) ^ (l15 & 7);
        ushort8 kb = *(const ushort8*)&Ks[cur][(j * 16 + l15) * 64 + g * 8];
        s[j] = mfma16(kb, qf[kk], s[j]);
      }
    }
    // causal mask (diagonal tile only); S already in exp2 domain
    const int qloc = w * 16 + l15;
    if (kt == qt) {
#pragma unroll
      for (int j = 0; j < 4; ++j)
#pragma unroll
        for (int r = 0; r < 4; ++r)
          if ((j * 16 + lhi * 4 + r) > qloc) s[j][r] = NEG_INF;
    }

    // in-lane softmax for q-row l15 (partials across lhi group)
    float pmax = s[0][0];
#pragma unroll
    for (int j = 0; j < 4; ++j)
#pragma unroll
      for (int r = 0; r < 4; ++r) pmax = fmaxf(pmax, s[j][r]);
    pmax = fmaxf(pmax, __shfl_xor(pmax, 16));
    pmax = fmaxf(pmax, __shfl_xor(pmax, 32));
    // defer-max: only rescale when the running max grew by > 8 (P <= 2^8)
    if (__any(pmax - m_s > 8.0f)) {
      const float mnew = fmaxf(m_s, pmax);
      const float al = exp2v(m_s - mnew);
      m_s = mnew;
      l_s *= al;
#pragma unroll
      for (int df = 0; df < 4; ++df)
#pragma unroll
        for (int r = 0; r < 4; ++r) o[df][r] *= al;
    }
    float rsum = 0.f;
#pragma unroll
    for (int j = 0; j < 4; ++j)
#pragma unroll
      for (int r = 0; r < 4; ++r) {
        const float pe = exp2v(s[j][r] - m_s);
        s[j][r] = pe;
        rsum += pe;
      }
    rsum += __shfl_xor(rsum, 16);
    rsum += __shfl_xor(rsum, 32);
    l_s += rsum;

    // P^T pack -> LDS (wave-private, swizzled b64 writes, cvt_pk)
#pragma unroll
    for (int j = 0; j < 4; ++j) {
      const unsigned int w0 = cvtpk(s[j][0], s[j][1]);
      const unsigned int w1 = cvtpk(s[j][2], s[j][3]);
      const u64_t dw = (u64_t)w0 | ((u64_t)w1 << 32);
      const int cg = j * 2 + (lhi >> 1);
      *(u64_t*)&myP[l15 * 72 + ((cg ^ swzP) << 3) + ((lhi & 1) << 2)] = dw;
    }

    // O^T += mfma(V^T-frag, P^T-frag)
#pragma unroll
    for (int kk = 0; kk < 2; ++kk) {
      ushort8 pa = *(const ushort8*)&myP[l15 * 72 + (((kk * 4 + lhi) ^ swzP) << 3)];
#pragma unroll
      for (int df = 0; df < 4; ++df) {
        const int r = df * 16 + l15;
        const int g = (kk * 4 + lhi) ^ ((r >> 3) & 7);
        ushort8 vb = *(const ushort8*)&Vt[cur][r * 72 + g * 8];
        o[df] = mfma16(vb, pa, o[df]);
      }
    }

    // write-late: V^T for next tile
    if (pf) {
#pragma unroll
      for (int it = 0; it < 2; ++it) {
        const int t0 = vt0b + it * 32;
        us4 av = __builtin_bit_cast(us4, va[it]);
        us4 cv = __builtin_bit_cast(us4, vc[it]);
#pragma unroll
        for (int i = 0; i < 4; ++i) {
          const int d = vd0 + i;
          const int scg = (t0 >> 3) ^ ((d >> 3) & 7);
          unsigned int wv = (unsigned int)av[i] | ((unsigned int)cv[i] << 16);
          *(unsigned int*)&Vt[nxt][d * 72 + scg * 8 + (t0 & 7)] = wv;
        }
      }
    }
    __syncthreads();
  }

  // epilogue: lane holds O^T[d = df*16+lhi*4+r][q = w*16+l15]
  const float inv = 1.0f / l_s;
  const size_t yrow = (size_t)(b * 2048 + qt * 64 + w * 16 + l15) * 1024 + h * 64;
#pragma unroll
  for (int df = 0; df < 4; ++df) {
    us4 ov;
#pragma unroll
    for (int r = 0; r < 4; ++r) ov[r] = f2bf(o[df][r] * inv);
    *(us4*)&Yb[yrow + df * 16 + lhi * 4] = ov;
  }
}

// ---------------- launch ----------------

extern "C" void kernel_launch(void* const* d_in, const int* in_sizes, int n_in,
                              void* d_out, int out_size, void* d_ws, size_t ws_size,
                              hipStream_t stream) {
  const float* x      = (const float*)d_in[0];
  const float* W_kqv  = (const float*)d_in[1];
  const float* b_kqv  = (const float*)d_in[2];
  const float* W_proj = (const float*)d_in[3];
  const float* b_proj = (const float*)d_in[4];
  float* out  = (float*)d_out;          // [B,T,C] fp32
  float* outK = out + 4194304;          // [B,H,T,D] fp32
  float* outV = out + 8388608;          // [B,H,T,D] fp32

  char* ws = (char*)d_ws;
  ushort_t* Xb  = (ushort_t*)(ws);
  ushort_t* Wkt = (ushort_t*)(ws + ((size_t)8 << 20));
  ushort_t* Wpt = (ushort_t*)(ws + ((size_t)14 << 20));
  ushort_t* Qb  = (ushort_t*)(ws + ((size_t)16 << 20));
  ushort_t* Kb  = (ushort_t*)(ws + ((size_t)24 << 20));
  ushort_t* Vb  = (ushort_t*)(ws + ((size_t)32 << 20));
  ushort_t* Yb  = Xb;  // Xb dead after QKV GEMM

  cast_x_kernel<<<2048, 256, 0, stream>>>(x, Xb, 524288);
  transpose_cast_kernel<<<dim3(96, 32), 256, 0, stream>>>(W_kqv, Wkt, 1024, 3072);
  transpose_cast_kernel<<<dim3(32, 32), 256, 0, stream>>>(W_proj, Wpt, 1024, 1024);
  gemm_bt_kernel<<<dim3(24, 32), 256, 0, stream>>>(
      Xb, Wkt, b_kqv, nullptr, outK, outV, Qb, Kb, Vb, 4096, 3072, 1024, 1);
  attn_kernel<<<1024, 256, 0, stream>>>(Qb, Kb, Vb, Yb);
  gemm_bt_kernel<<<dim3(8, 32), 256, 0, stream>>>(
      Yb, Wpt, b_proj, out, nullptr, nullptr, nullptr, nullptr, nullptr,
      4096, 1024, 1024, 0);
}

// Round 8
// 117.823 us; speedup vs baseline: 1.6115x; 1.1683x over previous
//
#include <hip/hip_runtime.h>

// Workspace layout (40 MB total):
//   [0,  8M)  Xb  bf16 [4096][1024]   (reused as Yb after QKV GEMM)
//   [8, 14M)  Wkqv_t bf16 [3072][1024]
//   [14,16M)  Wproj_t bf16 [1024][1024]
//   [16,24M)  Qb bf16 [B,H,T,D]  (pre-scaled by 0.125*log2e)
//   [24,32M)  Kb bf16 [B,H,T,D]
//   [32,40M)  Vb bf16 [B,H,T,D]

#define DEVI __device__ __forceinline__

typedef unsigned short ushort_t;
typedef unsigned long long u64_t;
typedef __attribute__((ext_vector_type(4))) unsigned short us4;
typedef __attribute__((ext_vector_type(8))) unsigned short ushort8;
typedef __attribute__((ext_vector_type(4))) float f32x4;
typedef __attribute__((ext_vector_type(8))) __bf16 bf16x8;

DEVI unsigned short f2bf(float f) {
  union { float f; unsigned int u; } c; c.f = f;
  unsigned int u = c.u;
  unsigned int r = (u + 0x7FFFu + ((u >> 16) & 1u)) >> 16;
  return (unsigned short)r;
}

// exp2 via raw v_exp_f32 (1 VALU trans op; s_nop covers the RAW hazard)
DEVI float exp2v(float x) {
  float r;
  asm("v_exp_f32 %0, %1\n\ts_nop 0" : "=v"(r) : "v"(x));
  return r;
}

// pack 2 fp32 -> 2 bf16 (RNE) in one instruction
DEVI unsigned int cvtpk(float lo, float hi) {
  unsigned int r;
  asm("v_cvt_pk_bf16_f32 %0, %1, %2" : "=v"(r) : "v"(lo), "v"(hi));
  return r;
}

DEVI f32x4 mfma16(ushort8 a, ushort8 b, f32x4 c) {
  return __builtin_amdgcn_mfma_f32_16x16x32_bf16(
      __builtin_bit_cast(bf16x8, a), __builtin_bit_cast(bf16x8, b), c, 0, 0, 0);
}

typedef const __attribute__((address_space(1))) void* gptr_t;
typedef __attribute__((address_space(3))) void* lptr_t;
#define GLOAD_LDS16(g, l) \
  __builtin_amdgcn_global_load_lds((gptr_t)(g), (lptr_t)(l), 16, 0, 0)

DEVI void bar() {
  asm volatile("" ::: "memory");
  __builtin_amdgcn_s_barrier();
  asm volatile("" ::: "memory");
}
#define VMCNT(n) asm volatile("s_waitcnt vmcnt(" #n ")" ::: "memory")

// ---------------- prep kernels ----------------

__global__ void cast_x_kernel(const float* __restrict__ in,
                              ushort_t* __restrict__ out, int n8) {
  int i = blockIdx.x * blockDim.x + threadIdx.x;
  if (i >= n8) return;
  const f32x4* p = (const f32x4*)in;
  f32x4 a = p[2 * i], b = p[2 * i + 1];
  ushort8 o;
  o[0] = f2bf(a[0]); o[1] = f2bf(a[1]); o[2] = f2bf(a[2]); o[3] = f2bf(a[3]);
  o[4] = f2bf(b[0]); o[5] = f2bf(b[1]); o[6] = f2bf(b[2]); o[7] = f2bf(b[3]);
  ((ushort8*)out)[i] = o;
}

// out[c][r] = bf16(in[r][c]); in is [R][Cin], out is [Cin][R]
__global__ void transpose_cast_kernel(const float* __restrict__ in,
                                      ushort_t* __restrict__ out, int R, int Cin) {
  __shared__ float tile[32][33];
  int c0 = blockIdx.x * 32, r0 = blockIdx.y * 32;
  int tx = threadIdx.x & 31, ty = threadIdx.x >> 5;
#pragma unroll
  for (int it = 0; it < 4; ++it)
    tile[ty + it * 8][tx] = in[(size_t)(r0 + ty + it * 8) * Cin + c0 + tx];
  __syncthreads();
#pragma unroll
  for (int it = 0; it < 4; ++it)
    out[(size_t)(c0 + ty + it * 8) * R + r0 + tx] = f2bf(tile[tx][ty + it * 8]);
}

// ---------------- GEMM: C = A[M,K] * Bt[N,K]^T + bias ----------------
// mode 0: write fp32 out[M][N]
// mode 1: QKV epilogue (scatter q/k/v; Qb pre-scaled by 0.125*log2e for attn)
// m97 structure: 128x128 tile, BK=64, SINGLE-buffered LDS (32 KB -> 5
// blocks/CU, whole grid resident), 2 barriers/kt, conflict-free XOR swizzle
// (source-swizzled global_load_lds + swizzled ds_read_b128), XCD swizzle.

__global__ __launch_bounds__(256) void gemm_bt_kernel(
    const ushort_t* __restrict__ A, const ushort_t* __restrict__ Bt,
    const float* __restrict__ bias, float* __restrict__ outF,
    float* __restrict__ outK, float* __restrict__ outV,
    ushort_t* __restrict__ Qb, ushort_t* __restrict__ Kb, ushort_t* __restrict__ Vb,
    int M, int N, int K, int mode) {
  __shared__ __align__(16) ushort_t As[128 * 64];
  __shared__ __align__(16) ushort_t Bs[128 * 64];
  const int tid = threadIdx.x;
  const int w = tid >> 6, lane = tid & 63;
  const int wr = w >> 1, wc = w & 1;
  // bijective XCD chunk swizzle (nwg divisible by 8)
  const int nbx = gridDim.x;
  const int nwg = nbx * gridDim.y;
  const int orig = blockIdx.x + nbx * blockIdx.y;
  const int tile = (orig & 7) * (nwg >> 3) + (orig >> 3);
  const int bx = tile % nbx, by = tile / nbx;
  const int m0 = by * 128, n0 = bx * 128;
  const int l15 = lane & 15, lhi = lane >> 4;
  const int rowA = lane >> 3;
  const int sgc = (((lane & 7) ^ ((lane >> 3) & 7)) << 3);

  f32x4 acc[4][4] = {};

  const int nk = K >> 6;
  for (int kt = 0; kt < nk; ++kt) {
    const size_t k0 = (size_t)kt << 6;
    if (kt) bar();  // prior compute done reading LDS
#pragma unroll
    for (int it = 0; it < 4; ++it) {
      const int rbase = (w * 4 + it) * 8;  // 8 rows per wave-call
      GLOAD_LDS16(A + (size_t)(m0 + rbase + rowA) * K + k0 + sgc, &As[rbase * 64]);
      GLOAD_LDS16(Bt + (size_t)(n0 + rbase + rowA) * K + k0 + sgc, &Bs[rbase * 64]);
    }
    VMCNT(0);
    bar();  // all waves' staging landed
#pragma unroll
    for (int kk = 0; kk < 2; ++kk) {
      const int gof = (((kk * 4 + lhi) ^ (l15 & 7)) << 3);
      ushort8 a[4], b[4];
#pragma unroll
      for (int i = 0; i < 4; ++i)
        a[i] = *(const ushort8*)&As[(wr * 64 + i * 16 + l15) * 64 + gof];
#pragma unroll
      for (int j = 0; j < 4; ++j)
        b[j] = *(const ushort8*)&Bs[(wc * 64 + j * 16 + l15) * 64 + gof];
#pragma unroll
      for (int i = 0; i < 4; ++i)
#pragma unroll
        for (int j = 0; j < 4; ++j) acc[i][j] = mfma16(a[i], b[j], acc[i][j]);
    }
  }

  const float QSCALE = 0.18033688011112042f;  // 0.125 * log2(e)
#pragma unroll
  for (int i = 0; i < 4; ++i) {
#pragma unroll
    for (int j = 0; j < 4; ++j) {
      const int nn = n0 + wc * 64 + j * 16 + l15;
      const float bv = bias[nn];
#pragma unroll
      for (int r = 0; r < 4; ++r) {
        const int mm = m0 + wr * 64 + i * 16 + lhi * 4 + r;
        const float v = acc[i][j][r] + bv;
        if (mode == 0) {
          outF[(size_t)mm * N + nn] = v;
        } else {
          const int bb = mm >> 11, t = mm & 2047;
          const int c = nn & 1023, h = c >> 6, d = c & 63;
          const size_t idx = ((size_t)(bb * 16 + h) * 2048 + t) * 64 + d;
          const int sec = nn >> 10;
          if (sec == 0) {
            Qb[idx] = f2bf(v * QSCALE);
          } else if (sec == 1) {
            outK[idx] = v; Kb[idx] = f2bf(v);
          } else {
            outV[idx] = v; Vb[idx] = f2bf(v);
          }
        }
      }
    }
  }
}

// ---------------- flash attention (swapped QK^T, in-lane softmax) ----------------
// Grid 1024 (one q-tile each), XCD-pinned (id%8 == bh%8), long-tiles-first.
// S^T = mfma(K,Q) in exp2 domain (Q pre-scaled by 0.125*log2e).
// Defer-max (THR=8): skip O-rescale while running max grows slowly.
// P-pack via v_cvt_pk_bf16_f32. K via swizzled global_load_lds; V^T reg-staged.

__global__ __launch_bounds__(256) void attn_kernel(
    const ushort_t* __restrict__ Qb, const ushort_t* __restrict__ Kb,
    const ushort_t* __restrict__ Vb, ushort_t* __restrict__ Yb) {
  __shared__ __align__(16) ushort_t Ks[2][64 * 64];   // K [t][d], chunk-swizzled
  __shared__ __align__(16) ushort_t Vt[2][64 * 72];   // V^T [d][t], swizzled
  __shared__ __align__(16) ushort_t Pl[4 * 16 * 72];  // per-wave P^T' [q][t], swizzled
  const int id = blockIdx.x;
  const int xcd = id & 7, win = id >> 3;
  const int qt = 31 - (win >> 2);     // longest blocks first
  const int bh = xcd + 8 * (win & 3);
  const int b = bh >> 4, h = bh & 15;
  const int tid = threadIdx.x, w = tid >> 6, lane = tid & 63;
  const int l15 = lane & 15, lhi = lane >> 4;
  const int swzP = 2 * (l15 & 3);
  const size_t base = (size_t)bh * 2048 * 64;
  const float NEG_INF = -__builtin_inff();
  ushort_t* myP = &Pl[w * 16 * 72];

  // V-staging thread geometry (per it: t0 = even row, 4 d's)
  const int vd0 = (tid & 15) * 4;
  const int vt0b = (tid >> 4) * 2;

  const int nkt = qt + 1;

  // Q fragments (B-operand): lane holds Q[q = w*16+l15][d = kk*32+lhi*8 ..]
  ushort8 qf[2];
  {
    const size_t qrow = base + (size_t)(qt * 64 + w * 16 + l15) * 64;
    qf[0] = *(const ushort8*)&Qb[qrow + lhi * 8];
    qf[1] = *(const ushort8*)&Qb[qrow + 32 + lhi * 8];
  }
  float m_s = NEG_INF, l_s = 0.f;
  f32x4 o[4] = {};

  // prologue: stage tile 0 into buf 0
  {
#pragma unroll
    for (int it = 0; it < 2; ++it) {
      const int chunk = tid + it * 256;
      const int row = chunk >> 3, g = chunk & 7;
      const int sg = g ^ (row & 7);
      GLOAD_LDS16(Kb + base + (size_t)row * 64 + sg * 8, &Ks[0][chunk * 8]);
    }
#pragma unroll
    for (int it = 0; it < 2; ++it) {
      const int t0 = vt0b + it * 32;
      const ushort_t* vp = Vb + base + (size_t)t0 * 64 + vd0;
      u64_t a = *(const u64_t*)vp;
      u64_t c = *(const u64_t*)(vp + 64);
      us4 av = __builtin_bit_cast(us4, a);
      us4 cv = __builtin_bit_cast(us4, c);
#pragma unroll
      for (int i = 0; i < 4; ++i) {
        const int d = vd0 + i;
        const int scg = (t0 >> 3) ^ ((d >> 3) & 7);
        unsigned int wv = (unsigned int)av[i] | ((unsigned int)cv[i] << 16);
        *(unsigned int*)&Vt[0][d * 72 + scg * 8 + (t0 & 7)] = wv;
      }
    }
  }
  __syncthreads();

  for (int kt = 0; kt < nkt; ++kt) {
    const int cur = kt & 1, nxt = cur ^ 1;
    const bool pf = (kt + 1 < nkt);
    u64_t va[2], vc[2];
    if (pf) {
      const size_t tb = base + (size_t)(kt + 1) * 64 * 64;
#pragma unroll
      for (int it = 0; it < 2; ++it) {
        const int chunk = tid + it * 256;
        const int row = chunk >> 3, g = chunk & 7;
        const int sg = g ^ (row & 7);
        GLOAD_LDS16(Kb + tb + (size_t)row * 64 + sg * 8, &Ks[nxt][chunk * 8]);
      }
#pragma unroll
      for (int it = 0; it < 2; ++it) {
        const int t0 = vt0b + it * 32;
        const ushort_t* vp = Vb + tb + (size_t)t0 * 64 + vd0;
        va[it] = *(const u64_t*)vp;
        vc[it] = *(const u64_t*)(vp + 64);
      }
    }

    // S^T = mfma(K, Q): s[j] rows t = j*16+lhi*4+r, col q = w*16+l15
    f32x4 s[4] = {};
#pragma unroll
    for (int kk = 0; kk < 2; ++kk) {
#pragma unroll
      for (int j = 0; j < 4; ++j) {
        const int g = (kk * 4 + lhi) ^ (l15 & 7);
        ushort8 kb = *(const ushort8*)&Ks[cur][(j * 16 + l15) * 64 + g * 8];
        s[j] = mfma16(kb, qf[kk], s[j]);
      }
    }
    // causal mask (diagonal tile only); S already in exp2 domain
    const int qloc = w * 16 + l15;
    if (kt == qt) {
#pragma unroll
      for (int j = 0; j < 4; ++j)
#pragma unroll
        for (int r = 0; r < 4; ++r)
          if ((j * 16 + lhi * 4 + r) > qloc) s[j][r] = NEG_INF;
    }

    // in-lane softmax for q-row l15 (partials across lhi group)
    float pmax = s[0][0];
#pragma unroll
    for (int j = 0; j < 4; ++j)
#pragma unroll
      for (int r = 0; r < 4; ++r) pmax = fmaxf(pmax, s[j][r]);
    pmax = fmaxf(pmax, __shfl_xor(pmax, 16));
    pmax = fmaxf(pmax, __shfl_xor(pmax, 32));
    // defer-max: only rescale when the running max grew by > 8 (P <= 2^8)
    if (__any(pmax - m_s > 8.0f)) {
      const float mnew = fmaxf(m_s, pmax);
      const float al = exp2v(m_s - mnew);
      m_s = mnew;
      l_s *= al;
#pragma unroll
      for (int df = 0; df < 4; ++df)
#pragma unroll
        for (int r = 0; r < 4; ++r) o[df][r] *= al;
    }
    float rsum = 0.f;
#pragma unroll
    for (int j = 0; j < 4; ++j)
#pragma unroll
      for (int r = 0; r < 4; ++r) {
        const float pe = exp2v(s[j][r] - m_s);
        s[j][r] = pe;
        rsum += pe;
      }
    rsum += __shfl_xor(rsum, 16);
    rsum += __shfl_xor(rsum, 32);
    l_s += rsum;

    // P^T pack -> LDS (wave-private, swizzled b64 writes, cvt_pk)
#pragma unroll
    for (int j = 0; j < 4; ++j) {
      const unsigned int w0 = cvtpk(s[j][0], s[j][1]);
      const unsigned int w1 = cvtpk(s[j][2], s[j][3]);
      const u64_t dw = (u64_t)w0 | ((u64_t)w1 << 32);
      const int cg = j * 2 + (lhi >> 1);
      *(u64_t*)&myP[l15 * 72 + ((cg ^ swzP) << 3) + ((lhi & 1) << 2)] = dw;
    }

    // O^T += mfma(V^T-frag, P^T-frag)
#pragma unroll
    for (int kk = 0; kk < 2; ++kk) {
      ushort8 pa = *(const ushort8*)&myP[l15 * 72 + (((kk * 4 + lhi) ^ swzP) << 3)];
#pragma unroll
      for (int df = 0; df < 4; ++df) {
        const int r = df * 16 + l15;
        const int g = (kk * 4 + lhi) ^ ((r >> 3) & 7);
        ushort8 vb = *(const ushort8*)&Vt[cur][r * 72 + g * 8];
        o[df] = mfma16(vb, pa, o[df]);
      }
    }

    // write-late: V^T for next tile
    if (pf) {
#pragma unroll
      for (int it = 0; it < 2; ++it) {
        const int t0 = vt0b + it * 32;
        us4 av = __builtin_bit_cast(us4, va[it]);
        us4 cv = __builtin_bit_cast(us4, vc[it]);
#pragma unroll
        for (int i = 0; i < 4; ++i) {
          const int d = vd0 + i;
          const int scg = (t0 >> 3) ^ ((d >> 3) & 7);
          unsigned int wv = (unsigned int)av[i] | ((unsigned int)cv[i] << 16);
          *(unsigned int*)&Vt[nxt][d * 72 + scg * 8 + (t0 & 7)] = wv;
        }
      }
    }
    __syncthreads();
  }

  // epilogue: lane holds O^T[d = df*16+lhi*4+r][q = w*16+l15]
  const float inv = 1.0f / l_s;
  const size_t yrow = (size_t)(b * 2048 + qt * 64 + w * 16 + l15) * 1024 + h * 64;
#pragma unroll
  for (int df = 0; df < 4; ++df) {
    us4 ov;
#pragma unroll
    for (int r = 0; r < 4; ++r) ov[r] = f2bf(o[df][r] * inv);
    *(us4*)&Yb[yrow + df * 16 + lhi * 4] = ov;
  }
}

// ---------------- launch ----------------

extern "C" void kernel_launch(void* const* d_in, const int* in_sizes, int n_in,
                              void* d_out, int out_size, void* d_ws, size_t ws_size,
                              hipStream_t stream) {
  const float* x      = (const float*)d_in[0];
  const float* W_kqv  = (const float*)d_in[1];
  const float* b_kqv  = (const float*)d_in[2];
  const float* W_proj = (const float*)d_in[3];
  const float* b_proj = (const float*)d_in[4];
  float* out  = (float*)d_out;          // [B,T,C] fp32
  float* outK = out + 4194304;          // [B,H,T,D] fp32
  float* outV = out + 8388608;          // [B,H,T,D] fp32

  char* ws = (char*)d_ws;
  ushort_t* Xb  = (ushort_t*)(ws);
  ushort_t* Wkt = (ushort_t*)(ws + ((size_t)8 << 20));
  ushort_t* Wpt = (ushort_t*)(ws + ((size_t)14 << 20));
  ushort_t* Qb  = (ushort_t*)(ws + ((size_t)16 << 20));
  ushort_t* Kb  = (ushort_t*)(ws + ((size_t)24 << 20));
  ushort_t* Vb  = (ushort_t*)(ws + ((size_t)32 << 20));
  ushort_t* Yb  = Xb;  // Xb dead after QKV GEMM

  cast_x_kernel<<<2048, 256, 0, stream>>>(x, Xb, 524288);
  transpose_cast_kernel<<<dim3(96, 32), 256, 0, stream>>>(W_kqv, Wkt, 1024, 3072);
  transpose_cast_kernel<<<dim3(32, 32), 256, 0, stream>>>(W_proj, Wpt, 1024, 1024);
  gemm_bt_kernel<<<dim3(24, 32), 256, 0, stream>>>(
      Xb, Wkt, b_kqv, nullptr, outK, outV, Qb, Kb, Vb, 4096, 3072, 1024, 1);
  attn_kernel<<<1024, 256, 0, stream>>>(Qb, Kb, Vb, Yb);
  gemm_bt_kernel<<<dim3(8, 32), 256, 0, stream>>>(
      Yb, Wpt, b_proj, out, nullptr, nullptr, nullptr, nullptr, nullptr,
      4096, 1024, 1024, 0);
}